// Round 2
// baseline (276.224 us; speedup 1.0000x reference)
//
#include <hip/hip_runtime.h>
#include <hip/hip_bf16.h>
#include <math.h>

typedef __bf16 bf16;
typedef __bf16 bf16x4 __attribute__((ext_vector_type(4)));
typedef __bf16 bf16x8 __attribute__((ext_vector_type(8)));
typedef float f32x4 __attribute__((ext_vector_type(4)));

static __device__ __forceinline__ f32x4 mfma16(bf16x8 a, bf16x8 b, f32x4 c) {
  return __builtin_amdgcn_mfma_f32_16x16x32_bf16(a, b, c, 0, 0, 0);
}

static __device__ __forceinline__ void gld_lds16(const void* g, void* l) {
  __builtin_amdgcn_global_load_lds(
      (const __attribute__((address_space(1))) void*)g,
      (__attribute__((address_space(3))) void*)l, 16, 0, 0);
}

// ---------------- cast f32 -> bf16, 4 elems/thread ----------------
__global__ void cast_f32_bf16(const float* __restrict__ in, bf16* __restrict__ out, int n4) {
  int i = blockIdx.x * blockDim.x + threadIdx.x;
  if (i < n4) {
    float4 v = reinterpret_cast<const float4*>(in)[i];
    bf16x4 o;
    o[0] = (bf16)v.x; o[1] = (bf16)v.y; o[2] = (bf16)v.z; o[3] = (bf16)v.w;
    reinterpret_cast<bf16x4*>(out)[i] = o;
  }
}

// ---------------- GEMM C = A @ B^T, A[M][K], B[N][K] bf16, 128x128 tile, BK=32 ----
// MODE 0: C bf16 written permuted to [b][h][t][d] (q/k/v), gridDim.z selects B/C.
// MODE 1: C f32 row-major [M][N].
template<int MODE>
__global__ void gemm_bt(const bf16* __restrict__ A,
                        const bf16* __restrict__ B0, const bf16* __restrict__ B1,
                        const bf16* __restrict__ B2,
                        void* __restrict__ C0v, void* __restrict__ C1v, void* __restrict__ C2v,
                        int M, int N, int K) {
  __shared__ bf16 As[128 * 32];
  __shared__ bf16 Bs[128 * 32];
  const int tid = threadIdx.x;
  const int wave = tid >> 6;
  const int lane = tid & 63;
  const int m0 = blockIdx.y * 128;
  const int n0 = blockIdx.x * 128;
  const int zz = blockIdx.z;
  const bf16* B = (zz == 0) ? B0 : (zz == 1) ? B1 : B2;
  void* Cv = (zz == 0) ? C0v : (zz == 1) ? C1v : C2v;
  const int wr = (wave >> 1) * 64;
  const int wc = (wave & 1) * 64;
  const int frow = lane & 15;
  const int fk = (lane >> 4) * 8;
  const int arow = wave * 16 + (lane >> 2);  // staging row within 64-row half
  const int acol = (lane & 3) * 8;           // staging col (elements)
  f32x4 acc[4][4] = {};
  char* AsB = (char*)As;
  char* BsB = (char*)Bs;
  for (int k0 = 0; k0 < K; k0 += 32) {
    __syncthreads();
    gld_lds16(&A[(size_t)(m0 + arow) * K + k0 + acol],      AsB + wave * 1024);
    gld_lds16(&A[(size_t)(m0 + 64 + arow) * K + k0 + acol], AsB + 4096 + wave * 1024);
    gld_lds16(&B[(size_t)(n0 + arow) * K + k0 + acol],      BsB + wave * 1024);
    gld_lds16(&B[(size_t)(n0 + 64 + arow) * K + k0 + acol], BsB + 4096 + wave * 1024);
    asm volatile("s_waitcnt vmcnt(0)" ::: "memory");
    __syncthreads();
    bf16x8 af[4], bfr[4];
#pragma unroll
    for (int mi = 0; mi < 4; ++mi)
      af[mi] = *reinterpret_cast<const bf16x8*>(&As[(wr + mi * 16 + frow) * 32 + fk]);
#pragma unroll
    for (int ni = 0; ni < 4; ++ni)
      bfr[ni] = *reinterpret_cast<const bf16x8*>(&Bs[(wc + ni * 16 + frow) * 32 + fk]);
#pragma unroll
    for (int mi = 0; mi < 4; ++mi)
#pragma unroll
      for (int ni = 0; ni < 4; ++ni)
        acc[mi][ni] = mfma16(af[mi], bfr[ni], acc[mi][ni]);
  }
#pragma unroll
  for (int mi = 0; mi < 4; ++mi) {
#pragma unroll
    for (int ni = 0; ni < 4; ++ni) {
#pragma unroll
      for (int r = 0; r < 4; ++r) {
        int row = m0 + wr + mi * 16 + (lane >> 4) * 4 + r;
        int col = n0 + wc + ni * 16 + frow;
        if (MODE == 0) {
          int b = row >> 11, t = row & 2047, h = col >> 6, d = col & 63;
          ((bf16*)Cv)[(((size_t)b * 16 + h) * 2048 + t) * 64 + d] = (bf16)acc[mi][ni][r];
        } else {
          ((float*)Cv)[(size_t)row * N + col] = acc[mi][ni][r];
        }
      }
    }
  }
}

// ---------------- transpose v [32][2048][64] -> vt [32][64][2048] ----------------
__global__ void transpose_v(const bf16* __restrict__ v, bf16* __restrict__ vt) {
  __shared__ bf16 tile[64][72];
  int bh = blockIdx.y;
  int t0 = blockIdx.x * 64;
  for (int idx = threadIdx.x; idx < 64 * 64; idx += 256) {
    int r = idx >> 6, c = idx & 63;
    tile[r][c] = v[((size_t)bh * 2048 + t0 + r) * 64 + c];
  }
  __syncthreads();
  for (int idx = threadIdx.x; idx < 64 * 64; idx += 256) {
    int d = idx >> 6, r = idx & 63;
    vt[((size_t)bh * 64 + d) * 2048 + t0 + r] = tile[r][d];
  }
}

// ---------------- flash attention + rotation/gate epilogue ----------------
// q,k: [32][2048][64] bf16; vt: [32][64][2048] bf16; comb: [2][2048][1024] bf16
__global__ void attn_kernel(const bf16* __restrict__ q, const bf16* __restrict__ k,
                            const bf16* __restrict__ vt,
                            const float* __restrict__ beta, const float* __restrict__ ivp,
                            const float* __restrict__ ovp, const float* __restrict__ chip,
                            bf16* __restrict__ comb) {
  __shared__ bf16 Ks[64][72];
  __shared__ bf16 VT[64][72];
  __shared__ bf16 Ps[4][16][72];
  const int tid = threadIdx.x;
  const int wave = tid >> 6, lane = tid & 63;
  const int bh = blockIdx.y, h = bh & 15, b = bh >> 4;
  const int q0 = blockIdx.x * 64 + wave * 16;
  const int frow = lane & 15, fk = (lane >> 4) * 8;
  const int reghi = (lane >> 4) * 4;
  const float inv_scale = 0.125f;  // 1/sqrt(dh*conv), conv = PHI^0 = 1
  bf16x8 qf[2];
  qf[0] = *reinterpret_cast<const bf16x8*>(&q[((size_t)bh * 2048 + q0 + frow) * 64 + fk]);
  qf[1] = *reinterpret_cast<const bf16x8*>(&q[((size_t)bh * 2048 + q0 + frow) * 64 + 32 + fk]);
  f32x4 acc[4] = {};
  float m_r[4], l_r[4];
#pragma unroll
  for (int r = 0; r < 4; ++r) { m_r[r] = -1e30f; l_r[r] = 0.f; }
  const int srow = tid >> 2, scol = (tid & 3) * 16;
  for (int k0 = 0; k0 < 2048; k0 += 64) {
    __syncthreads();
    {
      const bf16* kp = &k[((size_t)bh * 2048 + k0 + srow) * 64 + scol];
      *reinterpret_cast<bf16x8*>(&Ks[srow][scol])     = *reinterpret_cast<const bf16x8*>(kp);
      *reinterpret_cast<bf16x8*>(&Ks[srow][scol + 8]) = *reinterpret_cast<const bf16x8*>(kp + 8);
      const bf16* vp = &vt[((size_t)bh * 64 + srow) * 2048 + k0 + scol];
      *reinterpret_cast<bf16x8*>(&VT[srow][scol])     = *reinterpret_cast<const bf16x8*>(vp);
      *reinterpret_cast<bf16x8*>(&VT[srow][scol + 8]) = *reinterpret_cast<const bf16x8*>(vp + 8);
    }
    __syncthreads();
    float sc[4][4];
#pragma unroll
    for (int ni = 0; ni < 4; ++ni) {
      f32x4 z = {};
      bf16x8 kf0 = *reinterpret_cast<const bf16x8*>(&Ks[ni * 16 + frow][fk]);
      bf16x8 kf1 = *reinterpret_cast<const bf16x8*>(&Ks[ni * 16 + frow][32 + fk]);
      z = mfma16(qf[0], kf0, z);
      z = mfma16(qf[1], kf1, z);
#pragma unroll
      for (int r = 0; r < 4; ++r) sc[ni][r] = z[r] * inv_scale;
    }
    float rowmax[4];
#pragma unroll
    for (int r = 0; r < 4; ++r)
      rowmax[r] = fmaxf(fmaxf(sc[0][r], sc[1][r]), fmaxf(sc[2][r], sc[3][r]));
#pragma unroll
    for (int mask = 1; mask < 16; mask <<= 1)
#pragma unroll
      for (int r = 0; r < 4; ++r)
        rowmax[r] = fmaxf(rowmax[r], __shfl_xor(rowmax[r], mask));
    float esc[4];
#pragma unroll
    for (int r = 0; r < 4; ++r) {
      float mnew = fmaxf(m_r[r], rowmax[r]);
      esc[r] = __expf(m_r[r] - mnew);
      m_r[r] = mnew;
    }
    float rs[4] = {0.f, 0.f, 0.f, 0.f};
    float p[4][4];
#pragma unroll
    for (int ni = 0; ni < 4; ++ni)
#pragma unroll
      for (int r = 0; r < 4; ++r) {
        p[ni][r] = __expf(sc[ni][r] - m_r[r]);
        rs[r] += p[ni][r];
      }
#pragma unroll
    for (int mask = 1; mask < 16; mask <<= 1)
#pragma unroll
      for (int r = 0; r < 4; ++r) rs[r] += __shfl_xor(rs[r], mask);
#pragma unroll
    for (int r = 0; r < 4; ++r) l_r[r] = l_r[r] * esc[r] + rs[r];
#pragma unroll
    for (int f = 0; f < 4; ++f)
#pragma unroll
      for (int r = 0; r < 4; ++r) acc[f][r] *= esc[r];
#pragma unroll
    for (int ni = 0; ni < 4; ++ni)
#pragma unroll
      for (int r = 0; r < 4; ++r)
        Ps[wave][reghi + r][ni * 16 + frow] = (bf16)p[ni][r];
    __syncthreads();
    bf16x8 pf0 = *reinterpret_cast<const bf16x8*>(&Ps[wave][frow][fk]);
    bf16x8 pf1 = *reinterpret_cast<const bf16x8*>(&Ps[wave][frow][32 + fk]);
#pragma unroll
    for (int f = 0; f < 4; ++f) {
      bf16x8 v0 = *reinterpret_cast<const bf16x8*>(&VT[f * 16 + frow][fk]);
      bf16x8 v1 = *reinterpret_cast<const bf16x8*>(&VT[f * 16 + frow][32 + fk]);
      acc[f] = mfma16(pf0, v0, acc[f]);
      acc[f] = mfma16(pf1, v1, acc[f]);
    }
  }
  // epilogue: o = acc/l, rotation + gates, write combined
  float bb = 1.f / (1.f + expf(-beta[h]));
  float ang = 3.14159265358979323846f * bb;
  float ca = cosf(ang), sa = sinf(ang);
  float iv = 1.f / (1.f + expf(-ivp[h]));
  float ov = 1.f / (1.f + expf(-ovp[h]));
  float g = tanhf(chip[h]);
  float K1 = iv * ov * g * ca;
  float K2 = iv * ov * g * sa;
  float o[4][4];
#pragma unroll
  for (int f = 0; f < 4; ++f)
#pragma unroll
    for (int r = 0; r < 4; ++r) o[f][r] = acc[f][r] / l_r[r];
#pragma unroll
  for (int r = 0; r < 4; ++r) {
    int t = q0 + reghi + r;
    size_t base = ((size_t)b * 2048 + t) * 1024 + (size_t)h * 64;
#pragma unroll
    for (int f = 0; f < 2; ++f) {
      comb[base + f * 16 + frow]       = (bf16)(K1 * o[f][r] - K2 * o[f + 2][r]);
      comb[base + (f + 2) * 16 + frow] = (bf16)(K2 * o[f][r] + K1 * o[f + 2][r]);
    }
  }
}

extern "C" void kernel_launch(void* const* d_in, const int* in_sizes, int n_in,
                              void* d_out, int out_size, void* d_ws, size_t ws_size,
                              hipStream_t stream) {
  const float* x    = (const float*)d_in[0];
  const float* Wq   = (const float*)d_in[1];
  const float* Wk   = (const float*)d_in[2];
  const float* Wv   = (const float*)d_in[3];
  const float* We   = (const float*)d_in[4];
  const float* beta = (const float*)d_in[5];
  const float* ivp  = (const float*)d_in[6];
  const float* ovp  = (const float*)d_in[7];
  const float* chip = (const float*)d_in[8];

  char* ws = (char*)d_ws;
  bf16* x_bf  = (bf16*)(ws + (size_t)0);
  bf16* Wq_bf = (bf16*)(ws + ((size_t)8  << 20));
  bf16* Wk_bf = (bf16*)(ws + ((size_t)10 << 20));
  bf16* Wv_bf = (bf16*)(ws + ((size_t)12 << 20));
  bf16* We_bf = (bf16*)(ws + ((size_t)14 << 20));
  bf16* q_bf  = (bf16*)(ws + ((size_t)16 << 20));
  bf16* k_bf  = (bf16*)(ws + ((size_t)24 << 20));
  bf16* v_bf  = (bf16*)(ws + ((size_t)32 << 20));
  bf16* v_t   = (bf16*)(ws + ((size_t)40 << 20));
  bf16* comb  = (bf16*)(ws + ((size_t)48 << 20));

  cast_f32_bf16<<<4096, 256, 0, stream>>>(x,  x_bf,  4194304 / 4);
  cast_f32_bf16<<<1024, 256, 0, stream>>>(Wq, Wq_bf, 1048576 / 4);
  cast_f32_bf16<<<1024, 256, 0, stream>>>(Wk, Wk_bf, 1048576 / 4);
  cast_f32_bf16<<<1024, 256, 0, stream>>>(Wv, Wv_bf, 1048576 / 4);
  cast_f32_bf16<<<1024, 256, 0, stream>>>(We, We_bf, 1048576 / 4);

  gemm_bt<0><<<dim3(8, 32, 3), 256, 0, stream>>>(x_bf, Wq_bf, Wk_bf, Wv_bf,
                                                 q_bf, k_bf, v_bf, 4096, 1024, 1024);
  transpose_v<<<dim3(32, 32), 256, 0, stream>>>(v_bf, v_t);
  attn_kernel<<<dim3(32, 32), 256, 0, stream>>>(q_bf, k_bf, v_t, beta, ivp, ovp, chip, comb);
  gemm_bt<1><<<dim3(8, 32, 1), 256, 0, stream>>>(comb, We_bf, We_bf, We_bf,
                                                 d_out, d_out, d_out, 4096, 1024, 1024);
}

// Round 3
// 267.246 us; speedup vs baseline: 1.0336x; 1.0336x over previous
//
#include <hip/hip_runtime.h>
#include <hip/hip_bf16.h>
#include <math.h>

typedef __bf16 bf16;
typedef __bf16 bf16x4 __attribute__((ext_vector_type(4)));
typedef __bf16 bf16x8 __attribute__((ext_vector_type(8)));
typedef float f32x4 __attribute__((ext_vector_type(4)));

static __device__ __forceinline__ f32x4 mfma16(bf16x8 a, bf16x8 b, f32x4 c) {
  return __builtin_amdgcn_mfma_f32_16x16x32_bf16(a, b, c, 0, 0, 0);
}

static __device__ __forceinline__ void gld_lds16(const void* g, void* l) {
  __builtin_amdgcn_global_load_lds(
      (const __attribute__((address_space(1))) void*)g,
      (__attribute__((address_space(3))) void*)l, 16, 0, 0);
}

// ---------------- fused cast f32 -> bf16 for x + 4 weights ----------------
// x: 1048576 float4s, each W: 262144 float4s.
__global__ void cast_all(const float* __restrict__ x, const float* __restrict__ Wq,
                         const float* __restrict__ Wk, const float* __restrict__ Wv,
                         const float* __restrict__ We,
                         bf16* __restrict__ xb, bf16* __restrict__ qb,
                         bf16* __restrict__ kb, bf16* __restrict__ vb,
                         bf16* __restrict__ eb) {
  int i = blockIdx.x * 256 + threadIdx.x;
  const float* s; bf16* d; int off;
  if (i < 1048576) { s = x; d = xb; off = i; }
  else {
    int j = i - 1048576; int w = j >> 18; off = j & 262143;
    s = (w == 0) ? Wq : (w == 1) ? Wk : (w == 2) ? Wv : We;
    d = (w == 0) ? qb : (w == 1) ? kb : (w == 2) ? vb : eb;
  }
  float4 v = reinterpret_cast<const float4*>(s)[off];
  bf16x4 o; o[0] = (bf16)v.x; o[1] = (bf16)v.y; o[2] = (bf16)v.z; o[3] = (bf16)v.w;
  reinterpret_cast<bf16x4*>(d)[off] = o;
}

// ---------------- GEMM C = A @ B^T, 128x128 tile, BK=32, XCD-swizzled ----
// MODE 0: C bf16 permuted to [b][h][t][d] (q/k/v), z selects B/C. MODE 1: C f32 [M][N].
template<int MODE>
__global__ void gemm_bt(const bf16* __restrict__ A,
                        const bf16* __restrict__ B0, const bf16* __restrict__ B1,
                        const bf16* __restrict__ B2,
                        void* __restrict__ C0v, void* __restrict__ C1v, void* __restrict__ C2v,
                        int M, int N, int K) {
  __shared__ bf16 As[128 * 32];
  __shared__ bf16 Bs[128 * 32];
  const int tid = threadIdx.x;
  const int wave = tid >> 6;
  const int lane = tid & 63;
  // bijective XCD swizzle: grid is (8, 32, z), nwg = 256*z, nwg%8==0
  const int bid = blockIdx.x | (blockIdx.y << 3) | (blockIdx.z << 8);
  const int cpx = gridDim.z << 5;  // nwg/8
  const int swz = (bid & 7) * cpx + (bid >> 3);
  const int n0 = (swz & 7) * 128;
  const int m0 = ((swz >> 3) & 31) * 128;
  const int zz = swz >> 8;
  const bf16* B = (zz == 0) ? B0 : (zz == 1) ? B1 : B2;
  void* Cv = (zz == 0) ? C0v : (zz == 1) ? C1v : C2v;
  const int wr = (wave >> 1) * 64;
  const int wc = (wave & 1) * 64;
  const int frow = lane & 15;
  const int fk = (lane >> 4) * 8;
  const int arow = wave * 16 + (lane >> 2);
  const int acol = (lane & 3) * 8;
  f32x4 acc[4][4] = {};
  char* AsB = (char*)As;
  char* BsB = (char*)Bs;
  for (int k0 = 0; k0 < K; k0 += 32) {
    __syncthreads();
    gld_lds16(&A[(size_t)(m0 + arow) * K + k0 + acol],      AsB + wave * 1024);
    gld_lds16(&A[(size_t)(m0 + 64 + arow) * K + k0 + acol], AsB + 4096 + wave * 1024);
    gld_lds16(&B[(size_t)(n0 + arow) * K + k0 + acol],      BsB + wave * 1024);
    gld_lds16(&B[(size_t)(n0 + 64 + arow) * K + k0 + acol], BsB + 4096 + wave * 1024);
    asm volatile("s_waitcnt vmcnt(0)" ::: "memory");
    __syncthreads();
    bf16x8 af[4], bfr[4];
#pragma unroll
    for (int mi = 0; mi < 4; ++mi)
      af[mi] = *reinterpret_cast<const bf16x8*>(&As[(wr + mi * 16 + frow) * 32 + fk]);
#pragma unroll
    for (int ni = 0; ni < 4; ++ni)
      bfr[ni] = *reinterpret_cast<const bf16x8*>(&Bs[(wc + ni * 16 + frow) * 32 + fk]);
    __builtin_amdgcn_s_setprio(1);
#pragma unroll
    for (int mi = 0; mi < 4; ++mi)
#pragma unroll
      for (int ni = 0; ni < 4; ++ni)
        acc[mi][ni] = mfma16(af[mi], bfr[ni], acc[mi][ni]);
    __builtin_amdgcn_s_setprio(0);
  }
#pragma unroll
  for (int mi = 0; mi < 4; ++mi) {
#pragma unroll
    for (int ni = 0; ni < 4; ++ni) {
#pragma unroll
      for (int r = 0; r < 4; ++r) {
        int row = m0 + wr + mi * 16 + (lane >> 4) * 4 + r;
        int col = n0 + wc + ni * 16 + frow;
        if (MODE == 0) {
          int b = row >> 11, t = row & 2047, h = col >> 6, d = col & 63;
          ((bf16*)Cv)[(((size_t)b * 16 + h) * 2048 + t) * 64 + d] = (bf16)acc[mi][ni][r];
        } else {
          ((float*)Cv)[(size_t)row * N + col] = acc[mi][ni][r];
        }
      }
    }
  }
}

// ---------------- transpose v [32][2048][64] -> vt [32][64][2048] ----------------
__global__ void transpose_v(const bf16* __restrict__ v, bf16* __restrict__ vt) {
  __shared__ bf16 tile[64][65];  // 65: 8-way -> 2-way read conflicts
  int bh = blockIdx.y;
  int t0 = blockIdx.x * 64;
  for (int idx = threadIdx.x; idx < 64 * 64; idx += 256) {
    int r = idx >> 6, c = idx & 63;
    tile[r][c] = v[((size_t)bh * 2048 + t0 + r) * 64 + c];
  }
  __syncthreads();
  for (int idx = threadIdx.x; idx < 64 * 64; idx += 256) {
    int d = idx >> 6, r = idx & 63;
    vt[((size_t)bh * 64 + d) * 2048 + t0 + r] = tile[r][d];
  }
}

// ---------------- flash attention + rotation/gate epilogue ----------------
// q,k: [32][2048][64] bf16; vt: [32][64][2048] bf16; comb: [2][2048][1024] bf16
// K/V tiles: unpadded [64][64] in LDS, XOR 16B-slot swizzle (slot ^= row&7),
// staged by global_load_lds with pre-swizzled global source, double-buffered.
__global__ void attn_kernel(const bf16* __restrict__ q, const bf16* __restrict__ k,
                            const bf16* __restrict__ vt,
                            const float* __restrict__ beta, const float* __restrict__ ivp,
                            const float* __restrict__ ovp, const float* __restrict__ chip,
                            bf16* __restrict__ comb) {
  __shared__ bf16 Ks[2][64 * 64];
  __shared__ bf16 VT[2][64 * 64];
  __shared__ bf16 Ps[4][16][72];
  const int tid = threadIdx.x;
  const int wave = tid >> 6, lane = tid & 63;
  // XCD swizzle: grid (32 qblk, 32 bh), nwg=1024
  const int bid = blockIdx.x | (blockIdx.y << 5);
  const int swz = (bid & 7) * 128 + (bid >> 3);
  const int qblk = swz & 31, bh = swz >> 5;
  const int h = bh & 15, b = bh >> 4;
  const int q0 = qblk * 64 + wave * 16;
  const int frow = lane & 15, hi = lane >> 4, fk = hi * 8;
  const int sw = frow & 7;             // read-side slot swizzle (row&7 == frow&7 everywhere)
  const int s0 = (hi ^ sw) * 8;        // element offset of k-slot 0..3
  const int s1 = ((hi ^ 4) ^ sw) * 8;  // element offset of k-slot 4..7
  const int reghi = hi * 4;
  const float inv_scale = 0.125f;  // 1/sqrt(dh*conv), conv = PHI^0 = 1

  bf16x8 qf[2];
  qf[0] = *reinterpret_cast<const bf16x8*>(&q[((size_t)bh * 2048 + q0 + frow) * 64 + fk]);
  qf[1] = *reinterpret_cast<const bf16x8*>(&q[((size_t)bh * 2048 + q0 + frow) * 64 + 32 + fk]);

  f32x4 acc[4] = {};
  float m_r[4], l_r[4];
#pragma unroll
  for (int r = 0; r < 4; ++r) { m_r[r] = -1e30f; l_r[r] = 0.f; }

  const bf16* kbase = k + (size_t)bh * 2048 * 64;
  const bf16* vbase = vt + (size_t)bh * 64 * 2048;
  // staging: unit u = (j*4+wave)*64 + lane; row = u>>3, slot = lane&7; src slot = slot^(row&7)
  const int srow_lo = lane >> 3;            // row & 7
  const int scol = ((lane & 7) ^ srow_lo) * 8;  // pre-swizzled source column (elems)

  auto stage = [&](int buf, int k0) {
#pragma unroll
    for (int j = 0; j < 2; ++j) {
      int r = (j * 4 + wave) * 8 + srow_lo;
      gld_lds16(&kbase[(size_t)(k0 + r) * 64 + scol], (char*)&Ks[buf][0] + (j * 4 + wave) * 1024);
      gld_lds16(&vbase[(size_t)r * 2048 + k0 + scol], (char*)&VT[buf][0] + (j * 4 + wave) * 1024);
    }
  };

  stage(0, 0);
  int cur = 0;
  for (int k0 = 0; k0 < 2048; k0 += 64) {
    asm volatile("s_waitcnt vmcnt(0)" ::: "memory");
    __syncthreads();
    if (k0 + 64 < 2048) stage(cur ^ 1, k0 + 64);
    // ---- QK^T ----
    float sc[4][4];
    __builtin_amdgcn_s_setprio(1);
#pragma unroll
    for (int ni = 0; ni < 4; ++ni) {
      const bf16* krow = &Ks[cur][(ni * 16 + frow) * 64];
      bf16x8 kf0 = *reinterpret_cast<const bf16x8*>(krow + s0);
      bf16x8 kf1 = *reinterpret_cast<const bf16x8*>(krow + s1);
      f32x4 z = {};
      z = mfma16(qf[0], kf0, z);
      z = mfma16(qf[1], kf1, z);
#pragma unroll
      for (int r = 0; r < 4; ++r) sc[ni][r] = z[r] * inv_scale;
    }
    __builtin_amdgcn_s_setprio(0);
    // ---- online softmax (q = 4*hi + r rows, k = ni*16 + frow cols) ----
    float rowmax[4];
#pragma unroll
    for (int r = 0; r < 4; ++r)
      rowmax[r] = fmaxf(fmaxf(sc[0][r], sc[1][r]), fmaxf(sc[2][r], sc[3][r]));
#pragma unroll
    for (int mask = 1; mask < 16; mask <<= 1)
#pragma unroll
      for (int r = 0; r < 4; ++r)
        rowmax[r] = fmaxf(rowmax[r], __shfl_xor(rowmax[r], mask));
    float esc[4];
#pragma unroll
    for (int r = 0; r < 4; ++r) {
      float mnew = fmaxf(m_r[r], rowmax[r]);
      esc[r] = __expf(m_r[r] - mnew);
      m_r[r] = mnew;
    }
    float rs[4] = {0.f, 0.f, 0.f, 0.f};
    float p[4][4];
#pragma unroll
    for (int ni = 0; ni < 4; ++ni)
#pragma unroll
      for (int r = 0; r < 4; ++r) {
        p[ni][r] = __expf(sc[ni][r] - m_r[r]);
        rs[r] += p[ni][r];
      }
#pragma unroll
    for (int mask = 1; mask < 16; mask <<= 1)
#pragma unroll
      for (int r = 0; r < 4; ++r) rs[r] += __shfl_xor(rs[r], mask);
#pragma unroll
    for (int r = 0; r < 4; ++r) l_r[r] = l_r[r] * esc[r] + rs[r];
#pragma unroll
    for (int f = 0; f < 4; ++f)
#pragma unroll
      for (int r = 0; r < 4; ++r) acc[f][r] *= esc[r];
    // ---- P -> LDS (wave-private; no barrier needed) ----
#pragma unroll
    for (int ni = 0; ni < 4; ++ni)
#pragma unroll
      for (int r = 0; r < 4; ++r)
        Ps[wave][reghi + r][ni * 16 + frow] = (bf16)p[ni][r];
    bf16x8 pf0 = *reinterpret_cast<const bf16x8*>(&Ps[wave][frow][fk]);
    bf16x8 pf1 = *reinterpret_cast<const bf16x8*>(&Ps[wave][frow][32 + fk]);
    // ---- PV ----
    __builtin_amdgcn_s_setprio(1);
#pragma unroll
    for (int f = 0; f < 4; ++f) {
      const bf16* vrow = &VT[cur][(f * 16 + frow) * 64];
      bf16x8 v0 = *reinterpret_cast<const bf16x8*>(vrow + s0);
      bf16x8 v1 = *reinterpret_cast<const bf16x8*>(vrow + s1);
      acc[f] = mfma16(pf0, v0, acc[f]);
      acc[f] = mfma16(pf1, v1, acc[f]);
    }
    __builtin_amdgcn_s_setprio(0);
    cur ^= 1;
  }
  // ---- epilogue: normalize, rotate, gate, write combined ----
  float bb = 1.f / (1.f + expf(-beta[h]));
  float ang = 3.14159265358979323846f * bb;
  float ca = cosf(ang), sa = sinf(ang);
  float iv = 1.f / (1.f + expf(-ivp[h]));
  float ov = 1.f / (1.f + expf(-ovp[h]));
  float g = tanhf(chip[h]);
  float K1 = iv * ov * g * ca;
  float K2 = iv * ov * g * sa;
  float o[4][4];
#pragma unroll
  for (int f = 0; f < 4; ++f)
#pragma unroll
    for (int r = 0; r < 4; ++r) o[f][r] = acc[f][r] / l_r[r];
#pragma unroll
  for (int r = 0; r < 4; ++r) {
    int t = q0 + reghi + r;
    size_t base = ((size_t)b * 2048 + t) * 1024 + (size_t)h * 64;
#pragma unroll
    for (int f = 0; f < 2; ++f) {
      comb[base + f * 16 + frow]       = (bf16)(K1 * o[f][r] - K2 * o[f + 2][r]);
      comb[base + (f + 2) * 16 + frow] = (bf16)(K2 * o[f][r] + K1 * o[f + 2][r]);
    }
  }
}

extern "C" void kernel_launch(void* const* d_in, const int* in_sizes, int n_in,
                              void* d_out, int out_size, void* d_ws, size_t ws_size,
                              hipStream_t stream) {
  const float* x    = (const float*)d_in[0];
  const float* Wq   = (const float*)d_in[1];
  const float* Wk   = (const float*)d_in[2];
  const float* Wv   = (const float*)d_in[3];
  const float* We   = (const float*)d_in[4];
  const float* beta = (const float*)d_in[5];
  const float* ivp  = (const float*)d_in[6];
  const float* ovp  = (const float*)d_in[7];
  const float* chip = (const float*)d_in[8];

  char* ws = (char*)d_ws;
  bf16* x_bf  = (bf16*)(ws + (size_t)0);
  bf16* Wq_bf = (bf16*)(ws + ((size_t)8  << 20));
  bf16* Wk_bf = (bf16*)(ws + ((size_t)10 << 20));
  bf16* Wv_bf = (bf16*)(ws + ((size_t)12 << 20));
  bf16* We_bf = (bf16*)(ws + ((size_t)14 << 20));
  bf16* q_bf  = (bf16*)(ws + ((size_t)16 << 20));
  bf16* k_bf  = (bf16*)(ws + ((size_t)24 << 20));
  bf16* v_bf  = (bf16*)(ws + ((size_t)32 << 20));
  bf16* v_t   = (bf16*)(ws + ((size_t)40 << 20));
  bf16* comb  = (bf16*)(ws + ((size_t)48 << 20));

  cast_all<<<8192, 256, 0, stream>>>(x, Wq, Wk, Wv, We, x_bf, Wq_bf, Wk_bf, Wv_bf, We_bf);

  gemm_bt<0><<<dim3(8, 32, 3), 256, 0, stream>>>(x_bf, Wq_bf, Wk_bf, Wv_bf,
                                                 q_bf, k_bf, v_bf, 4096, 1024, 1024);
  transpose_v<<<dim3(32, 32), 256, 0, stream>>>(v_bf, v_t);
  attn_kernel<<<dim3(32, 32), 256, 0, stream>>>(q_bf, k_bf, v_t, beta, ivp, ovp, chip, comb);
  gemm_bt<1><<<dim3(8, 32, 1), 256, 0, stream>>>(comb, We_bf, We_bf, We_bf,
                                                 d_out, d_out, d_out, 4096, 1024, 1024);
}

// Round 5
// 218.355 us; speedup vs baseline: 1.2650x; 1.2239x over previous
//
#include <hip/hip_runtime.h>
#include <hip/hip_bf16.h>
#include <math.h>

typedef __bf16 bf16;
typedef __bf16 bf16x4 __attribute__((ext_vector_type(4)));
typedef __bf16 bf16x8 __attribute__((ext_vector_type(8)));
typedef float f32x4 __attribute__((ext_vector_type(4)));
typedef float f32x16 __attribute__((ext_vector_type(16)));
typedef unsigned int u32x4 __attribute__((ext_vector_type(4)));

static __device__ __forceinline__ f32x4 mfma16(bf16x8 a, bf16x8 b, f32x4 c) {
  return __builtin_amdgcn_mfma_f32_16x16x32_bf16(a, b, c, 0, 0, 0);
}
static __device__ __forceinline__ f32x16 mfma32(bf16x8 a, bf16x8 b, f32x16 c) {
  return __builtin_amdgcn_mfma_f32_32x32x16_bf16(a, b, c, 0, 0, 0);
}
static __device__ __forceinline__ void gld_lds16(const void* g, void* l) {
  __builtin_amdgcn_global_load_lds(
      (const __attribute__((address_space(1))) void*)g,
      (__attribute__((address_space(3))) void*)l, 16, 0, 0);
}
static __device__ __forceinline__ unsigned cvt_pk_bf16(float lo, float hi) {
  unsigned r;
  asm("v_cvt_pk_bf16_f32 %0, %1, %2" : "=v"(r) : "v"(lo), "v"(hi));
  return r;
}

// ---------------- fused cast f32 -> bf16 for x + 4 weights ----------------
__global__ void cast_all(const float* __restrict__ x, const float* __restrict__ Wq,
                         const float* __restrict__ Wk, const float* __restrict__ Wv,
                         const float* __restrict__ We,
                         bf16* __restrict__ xb, bf16* __restrict__ qb,
                         bf16* __restrict__ kb, bf16* __restrict__ vb,
                         bf16* __restrict__ eb) {
  int i = blockIdx.x * 256 + threadIdx.x;
  const float* s; bf16* d; int off;
  if (i < 1048576) { s = x; d = xb; off = i; }
  else {
    int j = i - 1048576; int w = j >> 18; off = j & 262143;
    s = (w == 0) ? Wq : (w == 1) ? Wk : (w == 2) ? Wv : We;
    d = (w == 0) ? qb : (w == 1) ? kb : (w == 2) ? vb : eb;
  }
  float4 v = reinterpret_cast<const float4*>(s)[off];
  bf16x4 o; o[0] = (bf16)v.x; o[1] = (bf16)v.y; o[2] = (bf16)v.z; o[3] = (bf16)v.w;
  reinterpret_cast<bf16x4*>(d)[off] = o;
}

// ---------------- GEMM C = A @ B^T, 128x128 tile, BK=32, XCD-swizzled ----
template<int MODE>
__global__ void gemm_bt(const bf16* __restrict__ A,
                        const bf16* __restrict__ B0, const bf16* __restrict__ B1,
                        const bf16* __restrict__ B2,
                        void* __restrict__ C0v, void* __restrict__ C1v, void* __restrict__ C2v,
                        int M, int N, int K) {
  __shared__ bf16 As[128 * 32];
  __shared__ bf16 Bs[128 * 32];
  const int tid = threadIdx.x;
  const int wave = tid >> 6;
  const int lane = tid & 63;
  const int bid = blockIdx.x | (blockIdx.y << 3) | (blockIdx.z << 8);
  const int cpx = gridDim.z << 5;  // nwg/8
  const int swz = (bid & 7) * cpx + (bid >> 3);
  const int n0 = (swz & 7) * 128;
  const int m0 = ((swz >> 3) & 31) * 128;
  const int zz = swz >> 8;
  const bf16* B = (zz == 0) ? B0 : (zz == 1) ? B1 : B2;
  void* Cv = (zz == 0) ? C0v : (zz == 1) ? C1v : C2v;
  const int wr = (wave >> 1) * 64;
  const int wc = (wave & 1) * 64;
  const int frow = lane & 15;
  const int fk = (lane >> 4) * 8;
  const int arow = wave * 16 + (lane >> 2);
  const int acol = (lane & 3) * 8;
  f32x4 acc[4][4] = {};
  char* AsB = (char*)As;
  char* BsB = (char*)Bs;
  for (int k0 = 0; k0 < K; k0 += 32) {
    __syncthreads();
    gld_lds16(&A[(size_t)(m0 + arow) * K + k0 + acol],      AsB + wave * 1024);
    gld_lds16(&A[(size_t)(m0 + 64 + arow) * K + k0 + acol], AsB + 4096 + wave * 1024);
    gld_lds16(&B[(size_t)(n0 + arow) * K + k0 + acol],      BsB + wave * 1024);
    gld_lds16(&B[(size_t)(n0 + 64 + arow) * K + k0 + acol], BsB + 4096 + wave * 1024);
    asm volatile("s_waitcnt vmcnt(0)" ::: "memory");
    __syncthreads();
    bf16x8 af[4], bfr[4];
#pragma unroll
    for (int mi = 0; mi < 4; ++mi)
      af[mi] = *reinterpret_cast<const bf16x8*>(&As[(wr + mi * 16 + frow) * 32 + fk]);
#pragma unroll
    for (int ni = 0; ni < 4; ++ni)
      bfr[ni] = *reinterpret_cast<const bf16x8*>(&Bs[(wc + ni * 16 + frow) * 32 + fk]);
    __builtin_amdgcn_s_setprio(1);
#pragma unroll
    for (int mi = 0; mi < 4; ++mi)
#pragma unroll
      for (int ni = 0; ni < 4; ++ni)
        acc[mi][ni] = mfma16(af[mi], bfr[ni], acc[mi][ni]);
    __builtin_amdgcn_s_setprio(0);
  }
#pragma unroll
  for (int mi = 0; mi < 4; ++mi) {
#pragma unroll
    for (int ni = 0; ni < 4; ++ni) {
#pragma unroll
      for (int r = 0; r < 4; ++r) {
        int row = m0 + wr + mi * 16 + (lane >> 4) * 4 + r;
        int col = n0 + wc + ni * 16 + frow;
        if (MODE == 0) {
          int b = row >> 11, t = row & 2047, h = col >> 6, d = col & 63;
          ((bf16*)Cv)[(((size_t)b * 16 + h) * 2048 + t) * 64 + d] = (bf16)acc[mi][ni][r];
        } else {
          ((float*)Cv)[(size_t)row * N + col] = acc[mi][ni][r];
        }
      }
    }
  }
}

// ---------------- transpose v [32][2048][64] -> vt [32][64][2048] ----------------
__global__ void transpose_v(const bf16* __restrict__ v, bf16* __restrict__ vt) {
  __shared__ bf16 tile[64][65];
  int bh = blockIdx.y;
  int t0 = blockIdx.x * 64;
  for (int idx = threadIdx.x; idx < 64 * 64; idx += 256) {
    int r = idx >> 6, c = idx & 63;
    tile[r][c] = v[((size_t)bh * 2048 + t0 + r) * 64 + c];
  }
  __syncthreads();
  for (int idx = threadIdx.x; idx < 64 * 64; idx += 256) {
    int d = idx >> 6, r = idx & 63;
    vt[((size_t)bh * 64 + d) * 2048 + t0 + r] = tile[r][d];
  }
}

// ---------------- flash attention, swapped-QK 32x32 structure ----------------
// q,k: [32][2048][64]; vt: [32][64][2048]; comb: [2][2048][1024]
// 4 waves x 32 q-rows = 128 q/block. KVBLK=64, K/V dbuf+XOR-swizzled in LDS.
// S = mfma32(K,Q): lane (hi,ln) holds S[k=crow(r,hi)+32kh][q=ln] -> softmax in-lane.
// P->bf16 A-frags via cvt_pk + v_permlane32_swap. PV = mfma32(P, V^T).
__global__ void attn_kernel(const bf16* __restrict__ q, const bf16* __restrict__ k,
                            const bf16* __restrict__ vt,
                            const float* __restrict__ beta, const float* __restrict__ ivp,
                            const float* __restrict__ ovp, const float* __restrict__ chip,
                            bf16* __restrict__ comb) {
  __shared__ bf16 Ks[2][64 * 64];
  __shared__ bf16 Vs[2][64 * 64];
  __shared__ float red[4][32];
  const int tid = threadIdx.x;
  const int wave = tid >> 6, lane = tid & 63;
  const int hi = lane >> 5, ln = lane & 31;
  // XCD swizzle over 512 blocks
  const int bid = blockIdx.x | (blockIdx.y << 4);
  const int swz = (bid & 7) * 64 + (bid >> 3);
  const int qblk = swz & 15, bh = swz >> 4;
  const int h = bh & 15, b = bh >> 4;
  const int q0w = qblk * 128 + wave * 32;
  const float C = 0.18033688011112042f;  // 0.125 * log2(e): scale folded into exp2

  // Q fragments (B-operand): col=ln -> q-row q0w+ln, c = ds*16 + 8*hi + i
  const bf16* qrow = q + ((size_t)bh * 2048 + q0w + ln) * 64 + hi * 8;
  bf16x8 qf[4];
#pragma unroll
  for (int ds = 0; ds < 4; ++ds)
    qf[ds] = *reinterpret_cast<const bf16x8*>(qrow + ds * 16);

  const bf16* kbase = k + (size_t)bh * 2048 * 64;
  const bf16* vbase = vt + (size_t)bh * 64 * 2048;
  const int srow = lane >> 3;                      // row within 8-row unit
  const int scol = ((lane & 7) ^ (srow & 7)) * 8;  // pre-swizzled source col (elems)

  f32x16 acc0 = {}, acc1 = {};
  float m_run = -1e30f, l_run = 0.f;

  auto stage = [&](int buf, int k0) {
#pragma unroll
    for (int j = 0; j < 2; ++j) {
      int u = wave * 2 + j;
      int r = u * 8 + srow;
      gld_lds16(&kbase[(size_t)(k0 + r) * 64 + scol], (char*)&Ks[buf][0] + u * 1024);
      gld_lds16(&vbase[(size_t)r * 2048 + k0 + scol], (char*)&Vs[buf][0] + u * 1024);
    }
  };

  stage(0, 0);
  int cur = 0;
  for (int k0 = 0; k0 < 2048; k0 += 64) {
    asm volatile("s_waitcnt vmcnt(0)" ::: "memory");
    __syncthreads();
    if (k0 + 64 < 2048) stage(cur ^ 1, k0 + 64);

    // ---- QK^T: S[k][q] over two 32-key halves ----
    f32x16 s[2];
    s[0] = (f32x16){}; s[1] = (f32x16){};
    const char* kb = (const char*)&Ks[cur][0];
    __builtin_amdgcn_s_setprio(1);
#pragma unroll
    for (int kh = 0; kh < 2; ++kh) {
      const int r = kh * 32 + ln;
      const int rx = (r & 7) << 4;
#pragma unroll
      for (int ds = 0; ds < 4; ++ds) {
        bf16x8 kf = *reinterpret_cast<const bf16x8*>(kb + r * 128 + ((ds * 32 + hi * 16) ^ rx));
        s[kh] = mfma32(kf, qf[ds], s[kh]);
      }
    }
    __builtin_amdgcn_s_setprio(0);

    // ---- online softmax, fully in-lane (q = ln) ----
    float tm = -1e30f;
#pragma unroll
    for (int kh = 0; kh < 2; ++kh)
#pragma unroll
      for (int r = 0; r < 16; ++r) tm = fmaxf(tm, s[kh][r]);
    tm = fmaxf(tm, __shfl_xor(tm, 32));
    if (!__all(tm - m_run <= 64.f)) {   // defer-max: THR=8 in scaled units
      float mnew = fmaxf(m_run, tm);
      float e = exp2f((m_run - mnew) * C);
      if (hi == 0) red[wave][ln] = e;
      asm volatile("s_waitcnt lgkmcnt(0)" ::: "memory");
#pragma unroll
      for (int r = 0; r < 16; ++r) {
        float er = red[wave][(r & 3) + 8 * (r >> 2) + 4 * hi];
        acc0[r] *= er; acc1[r] *= er;
      }
      l_run *= e;
      m_run = mnew;
    }
    float mC = m_run * C;
    float psum = 0.f;
#pragma unroll
    for (int kh = 0; kh < 2; ++kh)
#pragma unroll
      for (int r = 0; r < 16; ++r) {
        float p = exp2f(fmaf(s[kh][r], C, -mC));
        s[kh][r] = p;
        psum += p;
      }
    psum += __shfl_xor(psum, 32);
    l_run += psum;

    // ---- P->bf16 A-frags (cvt_pk + permlane32_swap) fused with PV ----
    const char* vb = (const char*)&Vs[cur][0];
#pragma unroll
    for (int ks = 0; ks < 4; ++ks) {
      const int kh = ks >> 1;
      const int b0 = 8 * (ks & 1);
      unsigned a0 = cvt_pk_bf16(s[kh][b0 + 0], s[kh][b0 + 1]);
      unsigned a1 = cvt_pk_bf16(s[kh][b0 + 4], s[kh][b0 + 5]);
      unsigned c0 = cvt_pk_bf16(s[kh][b0 + 2], s[kh][b0 + 3]);
      unsigned c1 = cvt_pk_bf16(s[kh][b0 + 6], s[kh][b0 + 7]);
      asm("v_permlane32_swap_b32 %0, %1" : "+v"(a0), "+v"(a1));
      asm("v_permlane32_swap_b32 %0, %1" : "+v"(c0), "+v"(c1));
      union { u32x4 u; bf16x8 v; } pf;
      pf.u[0] = a0; pf.u[1] = c0; pf.u[2] = a1; pf.u[3] = c1;
      __builtin_amdgcn_s_setprio(1);
#pragma unroll
      for (int dh = 0; dh < 2; ++dh) {
        const int r = dh * 32 + ln;
        bf16x8 vf = *reinterpret_cast<const bf16x8*>(
            vb + r * 128 + ((ks * 32 + hi * 16) ^ ((r & 7) << 4)));
        if (dh == 0) acc0 = mfma32(pf.v, vf, acc0);
        else         acc1 = mfma32(pf.v, vf, acc1);
      }
      __builtin_amdgcn_s_setprio(0);
    }
    cur ^= 1;
  }

  // ---- epilogue: normalize, rotate, gate, write ----
  if (hi == 0) red[wave][ln] = 1.f / l_run;
  asm volatile("s_waitcnt lgkmcnt(0)" ::: "memory");
  float bb = 1.f / (1.f + expf(-beta[h]));
  float ang = 3.14159265358979323846f * bb;
  float ca = cosf(ang), sa = sinf(ang);
  float iv = 1.f / (1.f + expf(-ivp[h]));
  float ov = 1.f / (1.f + expf(-ovp[h]));
  float g = tanhf(chip[h]);
  float K1 = iv * ov * g * ca;
  float K2 = iv * ov * g * sa;
#pragma unroll
  for (int r = 0; r < 16; ++r) {
    int qr = (r & 3) + 8 * (r >> 2) + 4 * hi;
    float inv = red[wave][qr];
    float o_r = acc0[r] * inv, o_i = acc1[r] * inv;
    size_t base = ((size_t)b * 2048 + q0w + qr) * 1024 + (size_t)h * 64;
    comb[base + ln]      = (bf16)(K1 * o_r - K2 * o_i);
    comb[base + 32 + ln] = (bf16)(K2 * o_r + K1 * o_i);
  }
}

extern "C" void kernel_launch(void* const* d_in, const int* in_sizes, int n_in,
                              void* d_out, int out_size, void* d_ws, size_t ws_size,
                              hipStream_t stream) {
  const float* x    = (const float*)d_in[0];
  const float* Wq   = (const float*)d_in[1];
  const float* Wk   = (const float*)d_in[2];
  const float* Wv   = (const float*)d_in[3];
  const float* We   = (const float*)d_in[4];
  const float* beta = (const float*)d_in[5];
  const float* ivp  = (const float*)d_in[6];
  const float* ovp  = (const float*)d_in[7];
  const float* chip = (const float*)d_in[8];

  char* ws = (char*)d_ws;
  bf16* x_bf  = (bf16*)(ws + (size_t)0);
  bf16* Wq_bf = (bf16*)(ws + ((size_t)8  << 20));
  bf16* Wk_bf = (bf16*)(ws + ((size_t)10 << 20));
  bf16* Wv_bf = (bf16*)(ws + ((size_t)12 << 20));
  bf16* We_bf = (bf16*)(ws + ((size_t)14 << 20));
  bf16* q_bf  = (bf16*)(ws + ((size_t)16 << 20));
  bf16* k_bf  = (bf16*)(ws + ((size_t)24 << 20));
  bf16* v_bf  = (bf16*)(ws + ((size_t)32 << 20));
  bf16* v_t   = (bf16*)(ws + ((size_t)40 << 20));
  bf16* comb  = (bf16*)(ws + ((size_t)48 << 20));

  cast_all<<<8192, 256, 0, stream>>>(x, Wq, Wk, Wv, We, x_bf, Wq_bf, Wk_bf, Wv_bf, We_bf);

  gemm_bt<0><<<dim3(8, 32, 3), 256, 0, stream>>>(x_bf, Wq_bf, Wk_bf, Wv_bf,
                                                 q_bf, k_bf, v_bf, 4096, 1024, 1024);
  transpose_v<<<dim3(32, 32), 256, 0, stream>>>(v_bf, v_t);
  attn_kernel<<<dim3(16, 32), 256, 0, stream>>>(q_bf, k_bf, v_t, beta, ivp, ovp, chip, comb);
  gemm_bt<1><<<dim3(8, 32, 1), 256, 0, stream>>>(comb, We_bf, We_bf, We_bf,
                                                 d_out, d_out, d_out, 4096, 1024, 1024);
}